// Round 1
// baseline (2408.566 us; speedup 1.0000x reference)
//
#include <hip/hip_runtime.h>

// Sizes
#define T 70
#define B 64
#define E 512
#define H 512
#define V 10000
#define TB (T*B)            // 4480
#define SLOT (H*B)          // 32768 floats per (t) state slot
#define LOGITS_N (T*B*V)    // 44800000
#define FLAG_STRIDE 32      // one flag per 128B to avoid line contention

__device__ __forceinline__ float ftanh(float x) {
    // tanh(x) = 1 - 2/(exp(2x)+1); saturates correctly at +/-inf
    float e = __expf(2.0f * x);
    return 1.0f - 2.0f / (e + 1.0f);
}

// ---------------------------------------------------------------------------
// 1) Embedding gather: X[t][b][e] (row-major) = emb_table[ids[t][b]][e]
// ---------------------------------------------------------------------------
__global__ __launch_bounds__(256) void gather_emb(const int* __restrict__ ids,
                                                  const float* __restrict__ emb,
                                                  float* __restrict__ X) {
    int i = blockIdx.x * 256 + threadIdx.x;       // float4 index
    if (i >= TB * (E / 4)) return;
    int tok = i >> 7;                             // E/4 = 128 float4 per token
    int e4 = i & 127;
    int id = ids[tok];
    ((float4*)X)[i] = ((const float4*)emb)[id * 128 + e4];
}

// ---------------------------------------------------------------------------
// 2) Transpose initial hidden (L,B,H) row-major -> k4-packed (H/4, B, 4) slots
// ---------------------------------------------------------------------------
__global__ __launch_bounds__(256) void hinit_k(const float* __restrict__ hidden,
                                               float* __restrict__ H0,
                                               float* __restrict__ H1) {
    int i = blockIdx.x * 256 + threadIdx.x;       // [0, 2*SLOT)
    if (i >= 2 * SLOT) return;
    int l = i >> 15, r = i & (SLOT - 1);
    int k4 = r >> 8, q = r & 255, b = q >> 2, kk = q & 3;
    int h = k4 * 4 + kk;
    float v = hidden[l * SLOT + b * H + h];
    (l ? H1 : H0)[r] = v;
}

// ---------------------------------------------------------------------------
// 3) P0 = X @ W0x.T + b0   -> layout (T, N=512, B=64)
// ---------------------------------------------------------------------------
__global__ __launch_bounds__(256) void gemm_p0(const float* __restrict__ X,
                                               const float* __restrict__ W0,
                                               const float* __restrict__ b0v,
                                               float* __restrict__ P0) {
    __shared__ float As[32][68];   // [k][b]
    __shared__ float Ws[32][68];   // [k][n]
    int t = blockIdx.y;
    int n0 = blockIdx.x * 64;
    int tid = threadIdx.x;
    int bq = tid & 15;    // b0 = bq*4
    int nq = tid >> 4;    // n local = nq*4
    const float* A = X + t * 64 * E;
    float acc[4][4] = {{0.f}};

    for (int kc = 0; kc < 512; kc += 32) {
        for (int i = tid; i < 512; i += 256) {
            int bb = i >> 3, kq = i & 7;
            float4 a = *(const float4*)(A + bb * E + kc + kq * 4);
            As[kq*4+0][bb] = a.x; As[kq*4+1][bb] = a.y;
            As[kq*4+2][bb] = a.z; As[kq*4+3][bb] = a.w;
        }
        for (int i = tid; i < 512; i += 256) {
            int nn = i >> 3, kq = i & 7;
            float4 w = *(const float4*)(W0 + (size_t)(n0 + nn) * 1024 + kc + kq * 4);
            Ws[kq*4+0][nn] = w.x; Ws[kq*4+1][nn] = w.y;
            Ws[kq*4+2][nn] = w.z; Ws[kq*4+3][nn] = w.w;
        }
        __syncthreads();
#pragma unroll
        for (int kk = 0; kk < 32; kk++) {
            float4 a = *(const float4*)&As[kk][bq * 4];
            float4 w = *(const float4*)&Ws[kk][nq * 4];
            acc[0][0] += a.x*w.x; acc[0][1] += a.x*w.y; acc[0][2] += a.x*w.z; acc[0][3] += a.x*w.w;
            acc[1][0] += a.y*w.x; acc[1][1] += a.y*w.y; acc[1][2] += a.y*w.z; acc[1][3] += a.y*w.w;
            acc[2][0] += a.z*w.x; acc[2][1] += a.z*w.y; acc[2][2] += a.z*w.z; acc[2][3] += a.z*w.w;
            acc[3][0] += a.w*w.x; acc[3][1] += a.w*w.y; acc[3][2] += a.w*w.z; acc[3][3] += a.w*w.w;
        }
        __syncthreads();
    }
#pragma unroll
    for (int j = 0; j < 4; j++) {
        int n = n0 + nq * 4 + j;
        float bias = b0v[n];
        float4 r = make_float4(acc[0][j] + bias, acc[1][j] + bias,
                               acc[2][j] + bias, acc[3][j] + bias);
        *(float4*)(P0 + (size_t)t * SLOT + n * 64 + bq * 4) = r;
    }
}

// ---------------------------------------------------------------------------
// 4) Persistent cooperative recurrence. One launch replaces 71.
//    Blocks 0..63  (L0): for s in 0..69:  h0[s] = tanh(P0[s] + W0h @ h0[s-1])
//    Blocks 64..127(L1): for t in 0..69:  h1[t] = tanh(b1 + W1x@h0[t] + W1h@h1[t-1])
//    Weights staged in LDS ONCE (L0: 16KB, L1: 32KB) and reused for all steps.
//    Cross-step ordering via per-step completion counters:
//      producer: __syncthreads -> agent-scope RELEASE fetch_add
//      consumer: relaxed poll -> agent-scope ACQUIRE load -> __syncthreads
//    flags[s*FS]      = # L0 blocks done with step s   (target 64)
//    flags[(T+t)*FS]  = # L1 blocks done with step t   (target 64)
// ---------------------------------------------------------------------------
__device__ __forceinline__ void flag_wait(int* flag, int target) {
    if (threadIdx.x == 0) {
        while (__hip_atomic_load(flag, __ATOMIC_RELAXED, __HIP_MEMORY_SCOPE_AGENT) < target)
            __builtin_amdgcn_s_sleep(2);
        (void)__hip_atomic_load(flag, __ATOMIC_ACQUIRE, __HIP_MEMORY_SCOPE_AGENT);
    }
    __syncthreads();   // all threads held until data visible
}

__device__ __forceinline__ void flag_post(int* flag) {
    __syncthreads();   // all block stores issued before publish
    if (threadIdx.x == 0)
        __hip_atomic_fetch_add(flag, 1, __ATOMIC_RELEASE, __HIP_MEMORY_SCOPE_AGENT);
}

__global__ __launch_bounds__(256) void chain_persist(const float* __restrict__ P0,
                                                     float* __restrict__ H0,
                                                     float* __restrict__ H1,
                                                     const float* __restrict__ W0,
                                                     const float* __restrict__ W1,
                                                     const float* __restrict__ b1v,
                                                     int* flags) {
    __shared__ float wsh[8 * 1024];   // L0 uses 8*512, L1 uses 8*1024
    int tid = threadIdx.x;
    int bid = blockIdx.x;
    int b = tid & 63;
    int wv = __builtin_amdgcn_readfirstlane(tid >> 6);

    if (bid < 64) {
        // ---- layer 0 ----
        int nbase = bid * 8;
        for (int i = tid; i < 1024; i += 256) {           // 8 rows x 128 float4
            int r = i >> 7, c4 = i & 127;
            *(float4*)&wsh[r * 512 + c4 * 4] =
                *(const float4*)(W0 + (size_t)(nbase + r) * 1024 + 512 + c4 * 4);
        }
        __syncthreads();
        int r0 = wv * 2, r1 = r0 + 1;
        const float* w0 = &wsh[r0 * 512];
        const float* w1 = &wsh[r1 * 512];
        int n0 = nbase + r0;

        for (int s = 0; s < T; s++) {
            if (s > 0) flag_wait(&flags[(s - 1) * FLAG_STRIDE], 64);
            const float4* A = (const float4*)(H0 + (size_t)s * SLOT);  // h0[s-1]
            float acc0 = P0[(size_t)s * SLOT + n0 * 64 + b];
            float acc1 = P0[(size_t)s * SLOT + (n0 + 1) * 64 + b];
#pragma unroll 4
            for (int k4 = 0; k4 < 128; k4++) {
                float4 a = A[k4 * 64 + b];
                float4 x = *(const float4*)&w0[k4 * 4];
                float4 y = *(const float4*)&w1[k4 * 4];
                acc0 += a.x * x.x + a.y * x.y + a.z * x.z + a.w * x.w;
                acc1 += a.x * y.x + a.y * y.y + a.z * y.z + a.w * y.w;
            }
            float o0 = ftanh(acc0), o1 = ftanh(acc1);
            float* dst = H0 + (size_t)(s + 1) * SLOT + (n0 >> 2) * 256 + b * 4 + (n0 & 3);
            dst[0] = o0; dst[1] = o1;
            flag_post(&flags[s * FLAG_STRIDE]);
        }
    } else {
        // ---- layer 1 ----
        int nbase = (bid - 64) * 8;
        for (int i = tid; i < 2048; i += 256) {           // 8 rows x 256 float4
            int r = i >> 8, c4 = i & 255;
            *(float4*)&wsh[r * 1024 + c4 * 4] =
                *(const float4*)(W1 + (size_t)(nbase + r) * 1024 + c4 * 4);
        }
        __syncthreads();
        int r0 = wv * 2, r1 = r0 + 1;
        const float* wa0 = &wsh[r0 * 1024];
        const float* wb0 = wa0 + 512;
        const float* wa1 = &wsh[r1 * 1024];
        const float* wb1 = wa1 + 512;
        int n0 = nbase + r0;
        float bia0 = b1v[n0], bia1 = b1v[n0 + 1];

        for (int t = 0; t < T; t++) {
            flag_wait(&flags[t * FLAG_STRIDE], 64);                       // h0[t] ready
            if (t > 0) flag_wait(&flags[(T + t - 1) * FLAG_STRIDE], 64);  // h1[t-1] ready
            const float4* Aa = (const float4*)(H0 + (size_t)(t + 1) * SLOT); // h0[t]
            const float4* Ab = (const float4*)(H1 + (size_t)t * SLOT);       // h1[t-1]
            float acc0 = bia0, acc1 = bia1;
#pragma unroll 4
            for (int k4 = 0; k4 < 128; k4++) {
                float4 a = Aa[k4 * 64 + b];
                float4 c = Ab[k4 * 64 + b];
                float4 xa = *(const float4*)&wa0[k4 * 4];
                float4 xb = *(const float4*)&wb0[k4 * 4];
                float4 ya = *(const float4*)&wa1[k4 * 4];
                float4 yb = *(const float4*)&wb1[k4 * 4];
                acc0 += a.x*xa.x + a.y*xa.y + a.z*xa.z + a.w*xa.w
                      + c.x*xb.x + c.y*xb.y + c.z*xb.z + c.w*xb.w;
                acc1 += a.x*ya.x + a.y*ya.y + a.z*ya.z + a.w*ya.w
                      + c.x*yb.x + c.y*yb.y + c.z*yb.z + c.w*yb.w;
            }
            float o0 = ftanh(acc0), o1 = ftanh(acc1);
            float* dst = H1 + (size_t)(t + 1) * SLOT + (n0 >> 2) * 256 + b * 4 + (n0 & 3);
            dst[0] = o0; dst[1] = o1;
            flag_post(&flags[(T + t) * FLAG_STRIDE]);
        }
    }
}

// ---------------------------------------------------------------------------
// 5) logits[t][b][v] = tanh(H1[t] @ Wout.T + bout)
// ---------------------------------------------------------------------------
__global__ __launch_bounds__(256) void gemm_logits(const float* __restrict__ H1,
                                                   const float* __restrict__ Wout,
                                                   const float* __restrict__ boutv,
                                                   float* __restrict__ out) {
    __shared__ float As[32][68];   // [k][b]
    __shared__ float Ws[32][68];   // [k][v]
    int t = blockIdx.y;
    int v0 = blockIdx.x * 64;
    int tid = threadIdx.x;
    int bq = tid & 15;
    int vq = tid >> 4;
    const float* A = H1 + (size_t)(t + 1) * SLOT;
    float acc[4][4] = {{0.f}};

    for (int kc = 0; kc < 512; kc += 32) {
        for (int i = tid; i < 512; i += 256) {
            float4 a = ((const float4*)A)[kc * 16 + i];    // contiguous k4-packed
            int k4 = i >> 6, bb = i & 63;
            As[k4*4+0][bb] = a.x; As[k4*4+1][bb] = a.y;
            As[k4*4+2][bb] = a.z; As[k4*4+3][bb] = a.w;
        }
        for (int i = tid; i < 512; i += 256) {
            int vv = i >> 3, kq = i & 7;
            int v = v0 + vv;
            float4 w = (v < V) ? *(const float4*)(Wout + (size_t)v * 512 + kc + kq * 4)
                               : make_float4(0.f, 0.f, 0.f, 0.f);
            Ws[kq*4+0][vv] = w.x; Ws[kq*4+1][vv] = w.y;
            Ws[kq*4+2][vv] = w.z; Ws[kq*4+3][vv] = w.w;
        }
        __syncthreads();
#pragma unroll
        for (int kk = 0; kk < 32; kk++) {
            float4 a = *(const float4*)&As[kk][bq * 4];
            float4 w = *(const float4*)&Ws[kk][vq * 4];
            acc[0][0] += a.x*w.x; acc[0][1] += a.x*w.y; acc[0][2] += a.x*w.z; acc[0][3] += a.x*w.w;
            acc[1][0] += a.y*w.x; acc[1][1] += a.y*w.y; acc[1][2] += a.y*w.z; acc[1][3] += a.y*w.w;
            acc[2][0] += a.z*w.x; acc[2][1] += a.z*w.y; acc[2][2] += a.z*w.z; acc[2][3] += a.z*w.w;
            acc[3][0] += a.w*w.x; acc[3][1] += a.w*w.y; acc[3][2] += a.w*w.z; acc[3][3] += a.w*w.w;
        }
        __syncthreads();
    }
    int vb = v0 + vq * 4;
    if (vb < V) {
        float4 bo = *(const float4*)(boutv + vb);
#pragma unroll
        for (int i = 0; i < 4; i++) {
            int b = bq * 4 + i;
            float4 r = make_float4(ftanh(acc[i][0] + bo.x),
                                   ftanh(acc[i][1] + bo.y),
                                   ftanh(acc[i][2] + bo.z),
                                   ftanh(acc[i][3] + bo.w));
            *(float4*)(out + ((size_t)t * 64 + b) * V + vb) = r;
        }
    }
}

// ---------------------------------------------------------------------------
// 6) Final hidden -> d_out tail, (L,B,H) row-major
// ---------------------------------------------------------------------------
__global__ __launch_bounds__(256) void hfinal_k(const float* __restrict__ H0,
                                                const float* __restrict__ H1,
                                                float* __restrict__ out) {
    int i = blockIdx.x * 256 + threadIdx.x;       // [0, 2*SLOT)
    if (i >= 2 * SLOT) return;
    int l = i >> 15, r = i & (SLOT - 1);
    int b = r >> 9, h = r & 511;
    const float* Hp = l ? H1 : H0;
    out[LOGITS_N + i] = Hp[(size_t)T * SLOT + (h >> 2) * 256 + b * 4 + (h & 3)];
}

// ---------------------------------------------------------------------------
extern "C" void kernel_launch(void* const* d_in, const int* in_sizes, int n_in,
                              void* d_out, int out_size, void* d_ws, size_t ws_size,
                              hipStream_t stream) {
    const int*   ids    = (const int*)d_in[0];
    const float* hidden = (const float*)d_in[1];
    const float* emb    = (const float*)d_in[2];
    const float* W0     = (const float*)d_in[3];
    const float* b0v    = (const float*)d_in[4];
    const float* W1     = (const float*)d_in[5];
    const float* b1v    = (const float*)d_in[6];
    const float* Wout   = (const float*)d_in[7];
    const float* boutv  = (const float*)d_in[8];
    float* out = (float*)d_out;
    float* ws  = (float*)d_ws;

    float* X  = ws;                                   // TB*E      = 2,293,760
    float* P0 = ws + 2293760;                         // T*SLOT    = 2,293,760
    float* H0 = ws + 4587520;                         // 71*SLOT   = 2,326,528
    float* H1 = ws + 6914048;                         // 71*SLOT   = 2,326,528
    int* flags = (int*)X;                             // X is dead after gemm_p0

    gather_emb<<<2240, 256, 0, stream>>>(ids, emb, X);
    hinit_k<<<256, 256, 0, stream>>>(hidden, H0, H1);
    gemm_p0<<<dim3(8, T), 256, 0, stream>>>(X, W0, b0v, P0);

    // zero the 140 step-completion counters (stream-ordered after gemm_p0's
    // last read of X, before the persistent chain)
    hipMemsetAsync(flags, 0, (size_t)(2 * T * FLAG_STRIDE) * sizeof(int), stream);

    void* cargs[] = { (void*)&P0, (void*)&H0, (void*)&H1,
                      (void*)&W0, (void*)&W1, (void*)&b1v, (void*)&flags };
    hipLaunchCooperativeKernel((void*)chain_persist, dim3(128), dim3(256),
                               cargs, 0, stream);

    gemm_logits<<<dim3(157, T), 256, 0, stream>>>(H1, Wout, boutv, out);
    hfinal_k<<<256, 256, 0, stream>>>(H0, H1, out);
}